// Round 1
// baseline (748.165 us; speedup 1.0000x reference)
//
#include <hip/hip_runtime.h>
#include <hip/hip_bf16.h>
#include <stdint.h>

#define B_    4
#define S_    4096
#define STXT_ 77
#define C_    1280
#define CC_   768
#define H_    20
#define TIP_  4
#define D_    64

using short8 = __attribute__((ext_vector_type(8))) short;
using f32x4  = __attribute__((ext_vector_type(4))) float;

__device__ __forceinline__ ushort f2bf(float f) {
  union { float f; uint32_t u; } x; x.f = f;
  uint32_t r = (x.u + 0x7FFFu + ((x.u >> 16) & 1u)) >> 16;
  return (ushort)r;
}

__device__ __forceinline__ void unpack8(uint4 u, float* dst) {
  dst[0] = __uint_as_float(u.x << 16); dst[1] = __uint_as_float(u.x & 0xFFFF0000u);
  dst[2] = __uint_as_float(u.y << 16); dst[3] = __uint_as_float(u.y & 0xFFFF0000u);
  dst[4] = __uint_as_float(u.z << 16); dst[5] = __uint_as_float(u.z & 0xFFFF0000u);
  dst[6] = __uint_as_float(u.w << 16); dst[7] = __uint_as_float(u.w & 0xFFFF0000u);
}

__device__ __forceinline__ void gload_lds16(ushort* lds, const ushort* g) {
  __builtin_amdgcn_global_load_lds(
      (const __attribute__((address_space(1))) void*)g,
      (__attribute__((address_space(3))) void*)lds, 16, 0, 0);
}

// ---------------- prep kernels ----------------

__global__ void convert_all(const float* __restrict__ hid, const float* __restrict__ enc,
                            const float* __restrict__ ipx, ushort* __restrict__ hb,
                            ushort* __restrict__ encb, ushort* __restrict__ ipb) {
  const size_t N0 = (size_t)B_ * S_ * C_;
  const size_t N1 = (size_t)B_ * STXT_ * CC_;
  const size_t N2 = (size_t)B_ * TIP_ * CC_;
  const size_t TOT4 = (N0 + N1 + N2) / 4;
  for (size_t i4 = (size_t)blockIdx.x * blockDim.x + threadIdx.x; i4 < TOT4;
       i4 += (size_t)gridDim.x * blockDim.x) {
    size_t i = i4 * 4;
    const float* src; ushort* dst; size_t off;
    if (i < N0)            { src = hid; dst = hb;   off = i; }
    else if (i < N0 + N1)  { src = enc; dst = encb; off = i - N0; }
    else                   { src = ipx; dst = ipb;  off = i - N0 - N1; }
    float4 v = *(const float4*)&src[off];
    ushort4 w;
    w.x = f2bf(v.x); w.y = f2bf(v.y); w.z = f2bf(v.z); w.w = f2bf(v.w);
    *(ushort4*)&dst[off] = w;
  }
}

// src [K][1280] f32 -> dst [1280][K] bf16
__global__ void transpose_weights(const float* __restrict__ wq, const float* __restrict__ wk,
                                  const float* __restrict__ wv, const float* __restrict__ wkip,
                                  const float* __restrict__ wvip, const float* __restrict__ wout,
                                  ushort* __restrict__ wqT, ushort* __restrict__ wkT,
                                  ushort* __restrict__ wvT, ushort* __restrict__ wkipT,
                                  ushort* __restrict__ wvipT, ushort* __restrict__ woutT) {
  __shared__ float t[32][33];
  const float* src; ushort* dst; int K;
  switch (blockIdx.z) {
    case 0:  src = wq;   dst = wqT;   K = C_;  break;
    case 1:  src = wk;   dst = wkT;   K = CC_; break;
    case 2:  src = wv;   dst = wvT;   K = CC_; break;
    case 3:  src = wkip; dst = wkipT; K = CC_; break;
    case 4:  src = wvip; dst = wvipT; K = CC_; break;
    default: src = wout; dst = woutT; K = C_;  break;
  }
  const int n0 = blockIdx.x * 32;
  const int k0 = blockIdx.y * 32;
  if (k0 >= K) return;
  const int tx = threadIdx.x, ty = threadIdx.y;
#pragma unroll
  for (int r = 0; r < 4; ++r) {
    int kk = k0 + ty + r * 8;
    t[ty + r * 8][tx] = src[(size_t)kk * C_ + n0 + tx];
  }
  __syncthreads();
#pragma unroll
  for (int r = 0; r < 4; ++r) {
    int nn = n0 + ty + r * 8;
    dst[(size_t)nn * K + k0 + tx] = f2bf(t[tx][ty + r * 8]);
  }
}

// region [B][S][77] f32 -> regionT [B][77][S] f32
__global__ void transpose_region(const float* __restrict__ region, float* __restrict__ regionT) {
  __shared__ float t[32][33];
  const int b = blockIdx.z;
  const int s0 = blockIdx.x * 32;
  const int k0 = blockIdx.y * 32;
  const int tx = threadIdx.x, ty = threadIdx.y;
#pragma unroll
  for (int r = 0; r < 4; ++r) {
    int ss = s0 + ty + r * 8;
    int kk = k0 + tx;
    t[ty + r * 8][tx] = (kk < STXT_) ? region[((size_t)b * S_ + ss) * STXT_ + kk] : 0.f;
  }
  __syncthreads();
#pragma unroll
  for (int r = 0; r < 4; ++r) {
    int kk = k0 + ty + r * 8;
    if (kk < STXT_)
      regionT[((size_t)b * STXT_ + kk) * S_ + s0 + tx] = t[tx][ty + r * 8];
  }
}

// ---------------- GEMM: C[M][N] = A[M][K] * Bt[N][K]^T ----------------
// OUTMODE 0: bf16 out, no bias.  OUTMODE 1: f32 out + bias.
template <int OUTMODE>
__global__ __launch_bounds__(256, 2)
void gemm_bt_k(const ushort* __restrict__ A, const ushort* __restrict__ Bt,
               void* __restrict__ Cout, const float* __restrict__ bias,
               int M, int N, int K) {
  __shared__ ushort As[128 * 32];
  __shared__ ushort Bs[128 * 32];
  const int tid  = threadIdx.x;
  const int lane = tid & 63;
  const int wid  = tid >> 6;
  const int tM = blockIdx.x * 128;
  const int tN = blockIdx.y * 128;
  const int wr = (wid >> 1) * 64, wc = (wid & 1) * 64;
  const int fr = lane & 15, fk = lane >> 4;

  f32x4 acc[4][4];
#pragma unroll
  for (int m = 0; m < 4; ++m)
#pragma unroll
    for (int n = 0; n < 4; ++n) acc[m][n] = (f32x4){0.f, 0.f, 0.f, 0.f};

  const int seg0 = tid, seg1 = tid + 256;
  const int r0 = seg0 >> 2, c0 = (seg0 & 3) * 8;
  const int r1 = seg1 >> 2, c1 = (seg1 & 3) * 8;
  int ra0 = tM + r0; if (ra0 >= M) ra0 = M - 1;
  int ra1 = tM + r1; if (ra1 >= M) ra1 = M - 1;
  const int rb0 = tN + r0, rb1 = tN + r1;

#pragma unroll 1
  for (int k0 = 0; k0 < K; k0 += 32) {
    gload_lds16(&As[seg0 * 8], &A[(size_t)ra0 * K + k0 + c0]);
    gload_lds16(&As[seg1 * 8], &A[(size_t)ra1 * K + k0 + c1]);
    gload_lds16(&Bs[seg0 * 8], &Bt[(size_t)rb0 * K + k0 + c0]);
    gload_lds16(&Bs[seg1 * 8], &Bt[(size_t)rb1 * K + k0 + c1]);
    __syncthreads();
    short8 af[4], bfr[4];
#pragma unroll
    for (int m = 0; m < 4; ++m)
      af[m] = *(const short8*)&As[(wr + m * 16 + fr) * 32 + fk * 8];
#pragma unroll
    for (int n = 0; n < 4; ++n)
      bfr[n] = *(const short8*)&Bs[(wc + n * 16 + fr) * 32 + fk * 8];
#pragma unroll
    for (int m = 0; m < 4; ++m)
#pragma unroll
      for (int n = 0; n < 4; ++n)
        acc[m][n] = __builtin_amdgcn_mfma_f32_16x16x32_bf16(af[m], bfr[n], acc[m][n], 0, 0, 0);
    __syncthreads();
  }

#pragma unroll
  for (int m = 0; m < 4; ++m) {
    const int rbase = tM + wr + m * 16 + (lane >> 4) * 4;
#pragma unroll
    for (int n = 0; n < 4; ++n) {
      const int col = tN + wc + n * 16 + (lane & 15);
#pragma unroll
      for (int j = 0; j < 4; ++j) {
        int row = rbase + j;
        if (row < M) {
          float v = acc[m][n][j];
          if (OUTMODE == 0) {
            ((ushort*)Cout)[(size_t)row * N + col] = f2bf(v);
          } else {
            ((float*)Cout)[(size_t)row * N + col] = v + bias[col];
          }
        }
      }
    }
  }
}

// ---------------- attention ----------------

__device__ __forceinline__ float dot64(const float* q, const float* k) {
  float s0 = 0.f, s1 = 0.f, s2 = 0.f, s3 = 0.f;
#pragma unroll
  for (int d = 0; d < 64; d += 4) {
    s0 = fmaf(q[d], k[d], s0);
    s1 = fmaf(q[d + 1], k[d + 1], s1);
    s2 = fmaf(q[d + 2], k[d + 2], s2);
    s3 = fmaf(q[d + 3], k[d + 3], s3);
  }
  return (s0 + s1) + (s2 + s3);
}

__global__ __launch_bounds__(256)
void stats_kernel(const ushort* __restrict__ qb, const ushort* __restrict__ kb,
                  float* __restrict__ stats) {
  __shared__ float Ks[STXT_][D_];
  const int b = blockIdx.x / H_, h = blockIdx.x % H_;
  const int qi = blockIdx.y * 256 + threadIdx.x;
  for (int c = threadIdx.x; c < STXT_ * 8; c += 256) {
    int t = c >> 3, d0 = (c & 7) * 8;
    uint4 u = *(const uint4*)&kb[(size_t)(b * STXT_ + t) * C_ + h * D_ + d0];
    unpack8(u, &Ks[t][d0]);
  }
  __syncthreads();
  float q[64];
  {
    const uint4* qr = (const uint4*)&qb[(size_t)(b * S_ + qi) * C_ + h * D_];
#pragma unroll
    for (int v = 0; v < 8; ++v) unpack8(qr[v], &q[v * 8]);
  }
  float sum = 0.f, sumsq = 0.f;
#pragma unroll 2
  for (int k = 0; k < STXT_; ++k) {
    float s = dot64(q, Ks[k]) * 0.125f;
    sum += s;
    sumsq = fmaf(s, s, sumsq);
  }
#pragma unroll
  for (int off = 32; off > 0; off >>= 1) {
    sum += __shfl_down(sum, off, 64);
    sumsq += __shfl_down(sumsq, off, 64);
  }
  if ((threadIdx.x & 63) == 0) {
    atomicAdd(&stats[0], sum);
    atomicAdd(&stats[1], sumsq);
  }
}

__global__ __launch_bounds__(256)
void attn_kernel(const ushort* __restrict__ qb, const ushort* __restrict__ kb,
                 const ushort* __restrict__ vb, const ushort* __restrict__ kipb,
                 const ushort* __restrict__ vipb, const float* __restrict__ regionT,
                 const float* __restrict__ stats, const float* __restrict__ sigma,
                 ushort* __restrict__ hb) {
  __shared__ float Ks[80][D_];
  __shared__ float Vs[80][D_];
  __shared__ float Kip[TIP_][D_];
  __shared__ float Vip[TIP_][D_];
  const int b = blockIdx.x / H_, h = blockIdx.x % H_;
  const int qi = blockIdx.y * 256 + threadIdx.x;

  for (int c = threadIdx.x; c < 80 * 8; c += 256) {
    int t = c >> 3, d0 = (c & 7) * 8;
    if (t < STXT_) {
      uint4 u = *(const uint4*)&kb[(size_t)(b * STXT_ + t) * C_ + h * D_ + d0];
      unpack8(u, &Ks[t][d0]);
      uint4 v = *(const uint4*)&vb[(size_t)(b * STXT_ + t) * C_ + h * D_ + d0];
      unpack8(v, &Vs[t][d0]);
    } else {
#pragma unroll
      for (int j = 0; j < 8; ++j) { Ks[t][d0 + j] = 0.f; Vs[t][d0 + j] = 0.f; }
    }
  }
  for (int c = threadIdx.x; c < TIP_ * 8; c += 256) {
    int t = c >> 3, d0 = (c & 7) * 8;
    uint4 u = *(const uint4*)&kipb[(size_t)(b * TIP_ + t) * C_ + h * D_ + d0];
    unpack8(u, &Kip[t][d0]);
    uint4 v = *(const uint4*)&vipb[(size_t)(b * TIP_ + t) * C_ + h * D_ + d0];
    unpack8(v, &Vip[t][d0]);
  }
  __syncthreads();

  float q[64];
  {
    const uint4* qr = (const uint4*)&qb[(size_t)(b * S_ + qi) * C_ + h * D_];
#pragma unroll
    for (int v = 0; v < 8; ++v) unpack8(qr[v], &q[v * 8]);
  }

  float bscale;
  {
    float sum = stats[0], sumsq = stats[1];
    const float Nf = (float)((double)B_ * H_ * S_ * STXT_);
    float var = (sumsq - sum * (sum / Nf)) / (Nf - 1.0f);
    bscale = sigma[0] * sqrtf(var);
  }
  const float* rrow = &regionT[(size_t)b * STXT_ * S_ + qi];

  float o[64];
#pragma unroll
  for (int d = 0; d < 64; ++d) o[d] = 0.f;
  float mrun = -1e30f, l = 0.f;

#pragma unroll 1
  for (int kc = 0; kc < 10; ++kc) {
    const int kbase = kc * 8;
    float sarr[8];
    float cmax = -1e30f;
#pragma unroll
    for (int j = 0; j < 8; ++j) {
      int k = kbase + j;
      float s;
      if (k < STXT_) {
        s = fmaf(rrow[(size_t)k * S_], bscale, dot64(q, Ks[k]) * 0.125f);
      } else {
        s = -1e30f;
      }
      sarr[j] = s;
      cmax = fmaxf(cmax, s);
    }
    if (cmax > mrun) {
      float sc = __expf(mrun - cmax);
      l *= sc;
#pragma unroll
      for (int d = 0; d < 64; ++d) o[d] *= sc;
      mrun = cmax;
    }
    float p[8];
#pragma unroll
    for (int j = 0; j < 8; ++j) { p[j] = __expf(sarr[j] - mrun); l += p[j]; }
#pragma unroll
    for (int j = 0; j < 8; ++j) {
      const float* vr = Vs[kbase + j];
      float pj = p[j];
#pragma unroll
      for (int d = 0; d < 64; ++d) o[d] = fmaf(pj, vr[d], o[d]);
    }
  }
  float rl = 1.0f / l;

  // IP stream (4 keys)
  float sip[TIP_];
  float mi = -1e30f;
#pragma unroll
  for (int t = 0; t < TIP_; ++t) {
    sip[t] = dot64(q, Kip[t]) * 0.125f;
    mi = fmaxf(mi, sip[t]);
  }
  float li = 0.f;
#pragma unroll
  for (int t = 0; t < TIP_; ++t) { sip[t] = __expf(sip[t] - mi); li += sip[t]; }
  float rli = 1.0f / li;

  uint4* orow = (uint4*)&hb[(size_t)(b * S_ + qi) * C_ + h * D_];
#pragma unroll
  for (int g = 0; g < 8; ++g) {
    float hv[8];
#pragma unroll
    for (int j = 0; j < 8; ++j) {
      int d = g * 8 + j;
      float acc = 0.f;
#pragma unroll
      for (int t = 0; t < TIP_; ++t) acc = fmaf(sip[t], Vip[t][d], acc);
      hv[j] = fmaf(acc, rli, o[d] * rl);
    }
    uint4 w;
    w.x = (uint)f2bf(hv[0]) | ((uint)f2bf(hv[1]) << 16);
    w.y = (uint)f2bf(hv[2]) | ((uint)f2bf(hv[3]) << 16);
    w.z = (uint)f2bf(hv[4]) | ((uint)f2bf(hv[5]) << 16);
    w.w = (uint)f2bf(hv[6]) | ((uint)f2bf(hv[7]) << 16);
    orow[g] = w;
  }
}

// ---------------- launcher ----------------

extern "C" void kernel_launch(void* const* d_in, const int* in_sizes, int n_in,
                              void* d_out, int out_size, void* d_ws, size_t ws_size,
                              hipStream_t stream) {
  const float* hid    = (const float*)d_in[0];
  const float* enc    = (const float*)d_in[1];
  const float* ipx    = (const float*)d_in[2];
  const float* region = (const float*)d_in[3];
  const float* sigma  = (const float*)d_in[4];
  const float* wq     = (const float*)d_in[5];
  const float* wk     = (const float*)d_in[6];
  const float* wv     = (const float*)d_in[7];
  const float* wkip   = (const float*)d_in[8];
  const float* wvip   = (const float*)d_in[9];
  const float* wout   = (const float*)d_in[10];
  const float* bout   = (const float*)d_in[11];

  char* ws = (char*)d_ws;
  size_t off = 0;
  auto alloc = [&](size_t bytes) {
    char* p = ws + off;
    off += (bytes + 255) & ~(size_t)255;
    return p;
  };
  float*  stats  = (float*)alloc(16);
  ushort* hb     = (ushort*)alloc((size_t)B_ * S_ * C_ * 2);       // hidden bf16, later h bf16
  ushort* qb     = (ushort*)alloc((size_t)B_ * S_ * C_ * 2);
  ushort* encb   = (ushort*)alloc((size_t)B_ * STXT_ * CC_ * 2);
  ushort* ipb    = (ushort*)alloc((size_t)B_ * TIP_ * CC_ * 2);
  ushort* wqT    = (ushort*)alloc((size_t)C_ * C_ * 2);
  ushort* wkT    = (ushort*)alloc((size_t)C_ * CC_ * 2);
  ushort* wvT    = (ushort*)alloc((size_t)C_ * CC_ * 2);
  ushort* wkipT  = (ushort*)alloc((size_t)C_ * CC_ * 2);
  ushort* wvipT  = (ushort*)alloc((size_t)C_ * CC_ * 2);
  ushort* woutT  = (ushort*)alloc((size_t)C_ * C_ * 2);
  ushort* kb     = (ushort*)alloc((size_t)B_ * STXT_ * C_ * 2);
  ushort* vb     = (ushort*)alloc((size_t)B_ * STXT_ * C_ * 2);
  ushort* kipb   = (ushort*)alloc((size_t)B_ * TIP_ * C_ * 2);
  ushort* vipb   = (ushort*)alloc((size_t)B_ * TIP_ * C_ * 2);
  float*  regionT= (float*)alloc((size_t)B_ * STXT_ * S_ * 4);

  hipMemsetAsync(stats, 0, 16, stream);
  convert_all<<<2048, 256, 0, stream>>>(hid, enc, ipx, hb, encb, ipb);
  transpose_weights<<<dim3(40, 40, 6), dim3(32, 8), 0, stream>>>(
      wq, wk, wv, wkip, wvip, wout, wqT, wkT, wvT, wkipT, wvipT, woutT);
  transpose_region<<<dim3(S_ / 32, 3, B_), dim3(32, 8), 0, stream>>>(region, regionT);

  gemm_bt_k<0><<<dim3(128, 10), 256, 0, stream>>>(hb,   wqT,   qb,   nullptr, B_ * S_,    C_, C_);
  gemm_bt_k<0><<<dim3(3, 10),   256, 0, stream>>>(encb, wkT,   kb,   nullptr, B_ * STXT_, C_, CC_);
  gemm_bt_k<0><<<dim3(3, 10),   256, 0, stream>>>(encb, wvT,   vb,   nullptr, B_ * STXT_, C_, CC_);
  gemm_bt_k<0><<<dim3(1, 10),   256, 0, stream>>>(ipb,  wkipT, kipb, nullptr, B_ * TIP_,  C_, CC_);
  gemm_bt_k<0><<<dim3(1, 10),   256, 0, stream>>>(ipb,  wvipT, vipb, nullptr, B_ * TIP_,  C_, CC_);

  stats_kernel<<<dim3(B_ * H_, S_ / 256), 256, 0, stream>>>(qb, kb, stats);
  attn_kernel<<<dim3(B_ * H_, S_ / 256), 256, 0, stream>>>(qb, kb, vb, kipb, vipb,
                                                           regionT, stats, sigma, hb);
  gemm_bt_k<1><<<dim3(128, 10), 256, 0, stream>>>(hb, woutT, d_out, bout, B_ * S_, C_, C_);
}

// Round 2
// 365.523 us; speedup vs baseline: 2.0468x; 2.0468x over previous
//
#include <hip/hip_runtime.h>
#include <hip/hip_bf16.h>
#include <stdint.h>

#define B_    4
#define S_    4096
#define STXT_ 77
#define C_    1280
#define CC_   768
#define H_    20
#define TIP_  4
#define D_    64
#define KVLD  2560

using short8 = __attribute__((ext_vector_type(8))) short;
using f32x4  = __attribute__((ext_vector_type(4))) float;

__device__ __forceinline__ ushort f2bf(float f) {
  union { float f; uint32_t u; } x; x.f = f;
  uint32_t r = (x.u + 0x7FFFu + ((x.u >> 16) & 1u)) >> 16;
  return (ushort)r;
}

__device__ __forceinline__ void gload_lds16(ushort* lds, const ushort* g) {
  __builtin_amdgcn_global_load_lds(
      (const __attribute__((address_space(1))) void*)g,
      (__attribute__((address_space(3))) void*)lds, 16, 0, 0);
}

// XOR-swizzle for bf16 [rows][64] LDS tiles (row stride 128B): spreads the
// 16-way same-bank column access across 8 16B slots.
__device__ __forceinline__ int kswz(int row, int colByte) {
  return row * 128 + (colByte ^ ((row & 7) << 4));
}

// ---------------- prep kernels ----------------

__global__ void convert_all(const float* __restrict__ hid, const float* __restrict__ enc,
                            const float* __restrict__ ipx, ushort* __restrict__ hb,
                            ushort* __restrict__ encb, ushort* __restrict__ ipb) {
  const size_t N0 = (size_t)B_ * S_ * C_;
  const size_t N1 = (size_t)B_ * STXT_ * CC_;
  const size_t N2 = (size_t)B_ * TIP_ * CC_;
  const size_t TOT4 = (N0 + N1 + N2) / 4;
  for (size_t i4 = (size_t)blockIdx.x * blockDim.x + threadIdx.x; i4 < TOT4;
       i4 += (size_t)gridDim.x * blockDim.x) {
    size_t i = i4 * 4;
    const float* src; ushort* dst; size_t off;
    if (i < N0)            { src = hid; dst = hb;   off = i; }
    else if (i < N0 + N1)  { src = enc; dst = encb; off = i - N0; }
    else                   { src = ipx; dst = ipb;  off = i - N0 - N1; }
    float4 v = *(const float4*)&src[off];
    ushort4 w;
    w.x = f2bf(v.x); w.y = f2bf(v.y); w.z = f2bf(v.z); w.w = f2bf(v.w);
    *(ushort4*)&dst[off] = w;
  }
}

// src [K][1280] f32 -> dst [1280][K] bf16 (z selects weight; K/V pairs merged)
__global__ void transpose_weights(const float* __restrict__ wq, const float* __restrict__ wk,
                                  const float* __restrict__ wv, const float* __restrict__ wkip,
                                  const float* __restrict__ wvip, const float* __restrict__ wout,
                                  ushort* __restrict__ wqT, ushort* __restrict__ wkvT,
                                  ushort* __restrict__ wkvipT, ushort* __restrict__ woutT) {
  __shared__ float t[32][33];
  const float* src; ushort* dst; int K;
  switch (blockIdx.z) {
    case 0:  src = wq;   dst = wqT;                           K = C_;  break;
    case 1:  src = wk;   dst = wkvT;                          K = CC_; break;
    case 2:  src = wv;   dst = wkvT + (size_t)C_ * CC_;       K = CC_; break;
    case 3:  src = wkip; dst = wkvipT;                        K = CC_; break;
    case 4:  src = wvip; dst = wkvipT + (size_t)C_ * CC_;     K = CC_; break;
    default: src = wout; dst = woutT;                         K = C_;  break;
  }
  const int n0 = blockIdx.x * 32;
  const int k0 = blockIdx.y * 32;
  if (k0 >= K) return;
  const int tx = threadIdx.x, ty = threadIdx.y;
#pragma unroll
  for (int r = 0; r < 4; ++r) {
    int kk = k0 + ty + r * 8;
    t[ty + r * 8][tx] = src[(size_t)kk * C_ + n0 + tx];
  }
  __syncthreads();
#pragma unroll
  for (int r = 0; r < 4; ++r) {
    int nn = n0 + ty + r * 8;
    dst[(size_t)nn * K + k0 + tx] = f2bf(t[tx][ty + r * 8]);
  }
}

// ---------------- GEMM: C[M][N] = A[M][K] * Bt[N][K]^T ----------------
// OUTMODE 0: bf16 out. 1: f32 out + bias. 2: bf16 out scaled by 0.125.
template <int OUTMODE>
__device__ __forceinline__ void gemm_body(const ushort* __restrict__ A,
                                          const ushort* __restrict__ Bt,
                                          void* __restrict__ Cout,
                                          const float* __restrict__ bias,
                                          int M, int N, int K, int tM, int tN,
                                          ushort* As, ushort* Bs) {
  const int tid  = threadIdx.x;
  const int lane = tid & 63;
  const int wid  = tid >> 6;
  const int wr = (wid >> 1) * 64, wc = (wid & 1) * 64;
  const int fr = lane & 15, fk = lane >> 4;

  f32x4 acc[4][4];
#pragma unroll
  for (int m = 0; m < 4; ++m)
#pragma unroll
    for (int n = 0; n < 4; ++n) acc[m][n] = (f32x4){0.f, 0.f, 0.f, 0.f};

  const int seg0 = tid, seg1 = tid + 256;
  const int r0 = seg0 >> 2, c0 = (seg0 & 3) * 8;
  const int r1 = seg1 >> 2, c1 = (seg1 & 3) * 8;
  int ra0 = tM + r0; if (ra0 >= M) ra0 = M - 1;
  int ra1 = tM + r1; if (ra1 >= M) ra1 = M - 1;
  const int rb0 = tN + r0, rb1 = tN + r1;

#pragma unroll 1
  for (int k0 = 0; k0 < K; k0 += 32) {
    gload_lds16(&As[seg0 * 8], &A[(size_t)ra0 * K + k0 + c0]);
    gload_lds16(&As[seg1 * 8], &A[(size_t)ra1 * K + k0 + c1]);
    gload_lds16(&Bs[seg0 * 8], &Bt[(size_t)rb0 * K + k0 + c0]);
    gload_lds16(&Bs[seg1 * 8], &Bt[(size_t)rb1 * K + k0 + c1]);
    __syncthreads();
    short8 af[4], bfr[4];
#pragma unroll
    for (int m = 0; m < 4; ++m)
      af[m] = *(const short8*)&As[(wr + m * 16 + fr) * 32 + fk * 8];
#pragma unroll
    for (int n = 0; n < 4; ++n)
      bfr[n] = *(const short8*)&Bs[(wc + n * 16 + fr) * 32 + fk * 8];
#pragma unroll
    for (int m = 0; m < 4; ++m)
#pragma unroll
      for (int n = 0; n < 4; ++n)
        acc[m][n] = __builtin_amdgcn_mfma_f32_16x16x32_bf16(af[m], bfr[n], acc[m][n], 0, 0, 0);
    __syncthreads();
  }

#pragma unroll
  for (int m = 0; m < 4; ++m) {
    const int rbase = tM + wr + m * 16 + (lane >> 4) * 4;
#pragma unroll
    for (int n = 0; n < 4; ++n) {
      const int col = tN + wc + n * 16 + (lane & 15);
#pragma unroll
      for (int j = 0; j < 4; ++j) {
        int row = rbase + j;
        if (row < M) {
          float v = acc[m][n][j];
          if (OUTMODE == 0) {
            ((ushort*)Cout)[(size_t)row * N + col] = f2bf(v);
          } else if (OUTMODE == 2) {
            ((ushort*)Cout)[(size_t)row * N + col] = f2bf(v * 0.125f);
          } else {
            ((float*)Cout)[(size_t)row * N + col] = v + bias[col];
          }
        }
      }
    }
  }
}

template <int OUTMODE>
__global__ __launch_bounds__(256, 2)
void gemm_bt_k(const ushort* __restrict__ A, const ushort* __restrict__ Bt,
               void* __restrict__ Cout, const float* __restrict__ bias,
               int M, int N, int K) {
  __shared__ ushort As[128 * 32];
  __shared__ ushort Bs[128 * 32];
  gemm_body<OUTMODE>(A, Bt, Cout, bias, M, N, K, blockIdx.x * 128, blockIdx.y * 128, As, Bs);
}

// z=0: K/V projection (M=308). z=1: IP K/V projection (M=16).
__global__ __launch_bounds__(256, 2)
void gemm_kv(const ushort* __restrict__ encb, const ushort* __restrict__ wkvT,
             ushort* __restrict__ kvb, const ushort* __restrict__ ipb,
             const ushort* __restrict__ wkvipT, ushort* __restrict__ ipkvb) {
  __shared__ ushort As[128 * 32];
  __shared__ ushort Bs[128 * 32];
  const ushort* A; const ushort* Bt; ushort* Co; int M;
  if (blockIdx.z == 0) { A = encb; Bt = wkvT;   Co = kvb;   M = B_ * STXT_; }
  else                 { A = ipb;  Bt = wkvipT; Co = ipkvb; M = B_ * TIP_;  }
  const int tM = blockIdx.x * 128;
  if (tM >= M) return;
  gemm_body<0>(A, Bt, Co, nullptr, M, KVLD, CC_, tM, blockIdx.y * 128, As, Bs);
}

// ---------------- attention (MFMA) ----------------
// Grid: (S/128 qtiles, B*H). Block: 256 thr = 4 waves, wave w owns rows w*32..+31.
// Key axis padded to 96: [0,77) text, [80,84) IP, rest zero.

__global__ __launch_bounds__(256, 4)
void stats_mfma(const ushort* __restrict__ qb, const ushort* __restrict__ kvb,
                float* __restrict__ stats) {
  __shared__ ushort Ks[80 * 64];
  __shared__ float part[4][2];
  const int qt = blockIdx.x, bh = blockIdx.y;
  const int b = bh / H_, h = bh % H_;
  const int tid = threadIdx.x, lane = tid & 63, wid = tid >> 6;
  for (int c = tid; c < 80 * 8; c += 256) {
    int row = c >> 3, col = (c & 7) * 8;
    uint4 v = {0, 0, 0, 0};
    if (row < STXT_)
      v = *(const uint4*)&kvb[(size_t)(b * STXT_ + row) * KVLD + h * D_ + col];
    *(uint4*)((char*)Ks + kswz(row, col * 2)) = v;
  }
  __syncthreads();
  const int fr = lane & 15, fk = lane >> 4;
  const int wr = wid * 32;
  short8 a0[2], a1[2];
#pragma unroll
  for (int m = 0; m < 2; ++m) {
    const ushort* qp = &qb[((size_t)b * S_ + qt * 128 + wr + m * 16 + fr) * C_ + h * D_];
    a0[m] = *(const short8*)&qp[fk * 8];
    a1[m] = *(const short8*)&qp[32 + fk * 8];
  }
  f32x4 acc[2][5];
#pragma unroll
  for (int m = 0; m < 2; ++m)
#pragma unroll
    for (int n = 0; n < 5; ++n) acc[m][n] = (f32x4){0.f, 0.f, 0.f, 0.f};
#pragma unroll
  for (int n = 0; n < 5; ++n) {
    short8 b0 = *(const short8*)((const char*)Ks + kswz(n * 16 + fr, fk * 16));
    short8 b1 = *(const short8*)((const char*)Ks + kswz(n * 16 + fr, 64 + fk * 16));
#pragma unroll
    for (int m = 0; m < 2; ++m) {
      acc[m][n] = __builtin_amdgcn_mfma_f32_16x16x32_bf16(a0[m], b0, acc[m][n], 0, 0, 0);
      acc[m][n] = __builtin_amdgcn_mfma_f32_16x16x32_bf16(a1[m], b1, acc[m][n], 0, 0, 0);
    }
  }
  float sum = 0.f, ss = 0.f;
#pragma unroll
  for (int m = 0; m < 2; ++m)
#pragma unroll
    for (int n = 0; n < 5; ++n)
#pragma unroll
      for (int j = 0; j < 4; ++j) {
        float v = acc[m][n][j];
        sum += v;
        ss = fmaf(v, v, ss);
      }
#pragma unroll
  for (int msk = 1; msk < 64; msk <<= 1) {
    sum += __shfl_xor(sum, msk, 64);
    ss  += __shfl_xor(ss,  msk, 64);
  }
  if (lane == 0) { part[wid][0] = sum; part[wid][1] = ss; }
  __syncthreads();
  if (tid == 0) {
    float s = 0.f, q2 = 0.f;
#pragma unroll
    for (int w = 0; w < 4; ++w) { s += part[w][0]; q2 += part[w][1]; }
    atomicAdd(&stats[0], s);
    atomicAdd(&stats[1], q2);
  }
}

__global__ __launch_bounds__(256, 2)
void attn_mfma(const ushort* __restrict__ qb, const ushort* __restrict__ kvb,
               const ushort* __restrict__ ipkvb, const float* __restrict__ region,
               const float* __restrict__ stats, const float* __restrict__ sigma,
               ushort* __restrict__ hb) {
  __shared__ ushort Ks[96 * 64];     // swizzled, keys 0-76 text / 80-83 IP / else 0
  __shared__ ushort Vt[64 * 104];    // V^T [d][k], stride 104 (conflict-free)
  __shared__ ushort Pl[128 * 104];   // probs [q][k], stride 104
  const int qt = blockIdx.x, bh = blockIdx.y;
  const int b = bh / H_, h = bh % H_;
  const int tid = threadIdx.x, lane = tid & 63, wid = tid >> 6;
  const int fr = lane & 15, fk = lane >> 4;
  const int wr = wid * 32;
  const float NINF = -1e30f;

  for (int c = tid; c < 96 * 8; c += 256) {
    int row = c >> 3, col = (c & 7) * 8;
    uint4 v = {0, 0, 0, 0};
    if (row < STXT_)
      v = *(const uint4*)&kvb[(size_t)(b * STXT_ + row) * KVLD + h * D_ + col];
    else if (row >= 80 && row < 80 + TIP_)
      v = *(const uint4*)&ipkvb[(size_t)(b * TIP_ + row - 80) * KVLD + h * D_ + col];
    *(uint4*)((char*)Ks + kswz(row, col * 2)) = v;
  }
  for (int c = tid; c < 96 * 64; c += 256) {
    int k = c >> 6, d = c & 63;
    ushort v = 0;
    if (k < STXT_)
      v = kvb[(size_t)(b * STXT_ + k) * KVLD + C_ + h * D_ + d];
    else if (k >= 80 && k < 80 + TIP_)
      v = ipkvb[(size_t)(b * TIP_ + k - 80) * KVLD + C_ + h * D_ + d];
    Vt[d * 104 + k] = v;
  }
  __syncthreads();

  short8 a0[2], a1[2];
#pragma unroll
  for (int m = 0; m < 2; ++m) {
    const ushort* qp = &qb[((size_t)b * S_ + qt * 128 + wr + m * 16 + fr) * C_ + h * D_];
    a0[m] = *(const short8*)&qp[fk * 8];
    a1[m] = *(const short8*)&qp[32 + fk * 8];
  }
  f32x4 acc[2][6];
#pragma unroll
  for (int m = 0; m < 2; ++m)
#pragma unroll
    for (int n = 0; n < 6; ++n) acc[m][n] = (f32x4){0.f, 0.f, 0.f, 0.f};
#pragma unroll
  for (int n = 0; n < 6; ++n) {
    short8 b0 = *(const short8*)((const char*)Ks + kswz(n * 16 + fr, fk * 16));
    short8 b1 = *(const short8*)((const char*)Ks + kswz(n * 16 + fr, 64 + fk * 16));
#pragma unroll
    for (int m = 0; m < 2; ++m) {
      acc[m][n] = __builtin_amdgcn_mfma_f32_16x16x32_bf16(a0[m], b0, acc[m][n], 0, 0, 0);
      acc[m][n] = __builtin_amdgcn_mfma_f32_16x16x32_bf16(a1[m], b1, acc[m][n], 0, 0, 0);
    }
  }

  float bscale;
  {
    float sum = stats[0], sumsq = stats[1];
    const float Nf = (float)((double)B_ * H_ * S_ * STXT_);
    float var = (sumsq - sum * (sum / Nf)) / (Nf - 1.0f);
    bscale = sigma[0] * sqrtf(var);
  }

  // softmax: per (m,j) a 16-lane-group row reduce; text (n<5) and IP (n=5) streams
#pragma unroll
  for (int m = 0; m < 2; ++m) {
#pragma unroll
    for (int j = 0; j < 4; ++j) {
      const int qrow = qt * 128 + wr + m * 16 + (lane >> 4) * 4 + j;
      const float* rbase = &region[((size_t)b * S_ + qrow) * STXT_];
      float s[6];
#pragma unroll
      for (int n = 0; n < 5; ++n) {
        int key = n * 16 + fr;
        float rg = (key < STXT_) ? rbase[key] : 0.f;
        s[n] = (key < STXT_) ? fmaf(rg, bscale, acc[m][n][j]) : NINF;
      }
      s[5] = (fr < TIP_) ? acc[m][5][j] : NINF;

      float mt = fmaxf(fmaxf(fmaxf(s[0], s[1]), fmaxf(s[2], s[3])), s[4]);
#pragma unroll
      for (int msk = 1; msk < 16; msk <<= 1) mt = fmaxf(mt, __shfl_xor(mt, msk, 64));
      float pt[5], lt = 0.f;
#pragma unroll
      for (int n = 0; n < 5; ++n) { pt[n] = __expf(s[n] - mt); lt += pt[n]; }
#pragma unroll
      for (int msk = 1; msk < 16; msk <<= 1) lt += __shfl_xor(lt, msk, 64);

      float mi = s[5];
      mi = fmaxf(mi, __shfl_xor(mi, 1, 64));
      mi = fmaxf(mi, __shfl_xor(mi, 2, 64));
      float pi = __expf(s[5] - mi);
      float li = pi;
      li += __shfl_xor(li, 1, 64);
      li += __shfl_xor(li, 2, 64);

      const float rlt = 1.f / lt;
      const int prow = wr + m * 16 + (lane >> 4) * 4 + j;
#pragma unroll
      for (int n = 0; n < 5; ++n) Pl[prow * 104 + n * 16 + fr] = f2bf(pt[n] * rlt);
      Pl[prow * 104 + 80 + fr] = (fr < TIP_) ? f2bf(pi / li) : (ushort)0;
    }
  }

  // PV over concatenated 96 keys (both streams pre-normalized)
  f32x4 o[2][4];
#pragma unroll
  for (int m = 0; m < 2; ++m)
#pragma unroll
    for (int n = 0; n < 4; ++n) o[m][n] = (f32x4){0.f, 0.f, 0.f, 0.f};
#pragma unroll
  for (int kc = 0; kc < 3; ++kc) {
    const int kb8 = kc * 32;
    short8 pa0 = *(const short8*)&Pl[(wr + fr) * 104 + kb8 + fk * 8];
    short8 pa1 = *(const short8*)&Pl[(wr + 16 + fr) * 104 + kb8 + fk * 8];
#pragma unroll
    for (int n = 0; n < 4; ++n) {
      short8 vf = *(const short8*)&Vt[(n * 16 + fr) * 104 + kb8 + fk * 8];
      o[0][n] = __builtin_amdgcn_mfma_f32_16x16x32_bf16(pa0, vf, o[0][n], 0, 0, 0);
      o[1][n] = __builtin_amdgcn_mfma_f32_16x16x32_bf16(pa1, vf, o[1][n], 0, 0, 0);
    }
  }

#pragma unroll
  for (int m = 0; m < 2; ++m)
#pragma unroll
    for (int n = 0; n < 4; ++n)
#pragma unroll
      for (int j = 0; j < 4; ++j) {
        int row = qt * 128 + wr + m * 16 + (lane >> 4) * 4 + j;
        hb[((size_t)b * S_ + row) * C_ + h * D_ + n * 16 + fr] = f2bf(o[m][n][j]);
      }
}

// ---------------- launcher ----------------

extern "C" void kernel_launch(void* const* d_in, const int* in_sizes, int n_in,
                              void* d_out, int out_size, void* d_ws, size_t ws_size,
                              hipStream_t stream) {
  const float* hid    = (const float*)d_in[0];
  const float* enc    = (const float*)d_in[1];
  const float* ipx    = (const float*)d_in[2];
  const float* region = (const float*)d_in[3];
  const float* sigma  = (const float*)d_in[4];
  const float* wq     = (const float*)d_in[5];
  const float* wk     = (const float*)d_in[6];
  const float* wv     = (const float*)d_in[7];
  const float* wkip   = (const float*)d_in[8];
  const float* wvip   = (const float*)d_in[9];
  const float* wout   = (const float*)d_in[10];
  const float* bout   = (const float*)d_in[11];

  char* ws = (char*)d_ws;
  size_t off = 0;
  auto alloc = [&](size_t bytes) {
    char* p = ws + off;
    off += (bytes + 255) & ~(size_t)255;
    return p;
  };
  float*  stats  = (float*)alloc(16);
  ushort* hb     = (ushort*)alloc((size_t)B_ * S_ * C_ * 2);   // hidden bf16, later h bf16
  ushort* qb     = (ushort*)alloc((size_t)B_ * S_ * C_ * 2);   // pre-scaled by 0.125
  ushort* encb   = (ushort*)alloc((size_t)B_ * STXT_ * CC_ * 2);
  ushort* ipb    = (ushort*)alloc((size_t)B_ * TIP_ * CC_ * 2);
  ushort* wqT    = (ushort*)alloc((size_t)C_ * C_ * 2);
  ushort* wkvT   = (ushort*)alloc((size_t)KVLD * CC_ * 2);
  ushort* wkvipT = (ushort*)alloc((size_t)KVLD * CC_ * 2);
  ushort* woutT  = (ushort*)alloc((size_t)C_ * C_ * 2);
  ushort* kvb    = (ushort*)alloc((size_t)B_ * STXT_ * KVLD * 2);
  ushort* ipkvb  = (ushort*)alloc((size_t)B_ * TIP_ * KVLD * 2);

  hipMemsetAsync(stats, 0, 16, stream);
  convert_all<<<2048, 256, 0, stream>>>(hid, enc, ipx, hb, encb, ipb);
  transpose_weights<<<dim3(40, 40, 6), dim3(32, 8), 0, stream>>>(
      wq, wk, wv, wkip, wvip, wout, wqT, wkvT, wkvipT, woutT);

  gemm_bt_k<2><<<dim3(128, 10), 256, 0, stream>>>(hb, wqT, qb, nullptr, B_ * S_, C_, C_);
  gemm_kv<<<dim3(3, 20, 2), 256, 0, stream>>>(encb, wkvT, kvb, ipb, wkvipT, ipkvb);

  stats_mfma<<<dim3(S_ / 128, B_ * H_), 256, 0, stream>>>(qb, kvb, stats);
  attn_mfma<<<dim3(S_ / 128, B_ * H_), 256, 0, stream>>>(qb, kvb, ipkvb, region,
                                                         stats, sigma, hb);
  gemm_bt_k<1><<<dim3(128, 10), 256, 0, stream>>>(hb, woutT, d_out, bout, B_ * S_, C_, C_);
}

// Round 3
// 346.367 us; speedup vs baseline: 2.1600x; 1.0553x over previous
//
#include <hip/hip_runtime.h>
#include <hip/hip_bf16.h>
#include <stdint.h>

#define B_    4
#define S_    4096
#define STXT_ 77
#define C_    1280
#define CC_   768
#define H_    20
#define TIP_  4
#define D_    64
#define KVLD  2560

using short8 = __attribute__((ext_vector_type(8))) short;
using f32x4  = __attribute__((ext_vector_type(4))) float;

__device__ __forceinline__ ushort f2bf(float f) {
  union { float f; uint32_t u; } x; x.f = f;
  uint32_t r = (x.u + 0x7FFFu + ((x.u >> 16) & 1u)) >> 16;
  return (ushort)r;
}

__device__ __forceinline__ void gload_lds16(ushort* lds, const ushort* g) {
  __builtin_amdgcn_global_load_lds(
      (const __attribute__((address_space(1))) void*)g,
      (__attribute__((address_space(3))) void*)lds, 16, 0, 0);
}

// XOR-swizzle for bf16 [rows][64] LDS tiles (row stride 128B)
__device__ __forceinline__ int kswz(int row, int colByte) {
  return row * 128 + (colByte ^ ((row & 7) << 4));
}

// ---------------- prep kernels ----------------

__global__ void convert_all(const float* __restrict__ hid, const float* __restrict__ enc,
                            const float* __restrict__ ipx, ushort* __restrict__ hb,
                            ushort* __restrict__ encb, ushort* __restrict__ ipb) {
  const size_t N0 = (size_t)B_ * S_ * C_;
  const size_t N1 = (size_t)B_ * STXT_ * CC_;
  const size_t N2 = (size_t)B_ * TIP_ * CC_;
  const size_t TOT4 = (N0 + N1 + N2) / 4;
  for (size_t i4 = (size_t)blockIdx.x * blockDim.x + threadIdx.x; i4 < TOT4;
       i4 += (size_t)gridDim.x * blockDim.x) {
    size_t i = i4 * 4;
    const float* src; ushort* dst; size_t off;
    if (i < N0)            { src = hid; dst = hb;   off = i; }
    else if (i < N0 + N1)  { src = enc; dst = encb; off = i - N0; }
    else                   { src = ipx; dst = ipb;  off = i - N0 - N1; }
    float4 v = *(const float4*)&src[off];
    ushort4 w;
    w.x = f2bf(v.x); w.y = f2bf(v.y); w.z = f2bf(v.z); w.w = f2bf(v.w);
    *(ushort4*)&dst[off] = w;
  }
}

// src [K][1280] f32 -> dst [1280][K] bf16 (z selects weight; K/V pairs merged)
__global__ void transpose_weights(const float* __restrict__ wq, const float* __restrict__ wk,
                                  const float* __restrict__ wv, const float* __restrict__ wkip,
                                  const float* __restrict__ wvip, const float* __restrict__ wout,
                                  ushort* __restrict__ wqT, ushort* __restrict__ wkvT,
                                  ushort* __restrict__ wkvipT, ushort* __restrict__ woutT) {
  __shared__ float t[32][33];
  const float* src; ushort* dst; int K;
  switch (blockIdx.z) {
    case 0:  src = wq;   dst = wqT;                           K = C_;  break;
    case 1:  src = wk;   dst = wkvT;                          K = CC_; break;
    case 2:  src = wv;   dst = wkvT + (size_t)C_ * CC_;       K = CC_; break;
    case 3:  src = wkip; dst = wkvipT;                        K = CC_; break;
    case 4:  src = wvip; dst = wkvipT + (size_t)C_ * CC_;     K = CC_; break;
    default: src = wout; dst = woutT;                         K = C_;  break;
  }
  const int n0 = blockIdx.x * 32;
  const int k0 = blockIdx.y * 32;
  if (k0 >= K) return;
  const int tx = threadIdx.x, ty = threadIdx.y;
#pragma unroll
  for (int r = 0; r < 4; ++r) {
    int kk = k0 + ty + r * 8;
    t[ty + r * 8][tx] = src[(size_t)kk * C_ + n0 + tx];
  }
  __syncthreads();
#pragma unroll
  for (int r = 0; r < 4; ++r) {
    int nn = n0 + ty + r * 8;
    dst[(size_t)nn * K + k0 + tx] = f2bf(t[tx][ty + r * 8]);
  }
}

// ------- small-GEMM path (K/V + IP projections), unchanged m97-style -------
template <int OUTMODE>
__device__ __forceinline__ void gemm_body(const ushort* __restrict__ A,
                                          const ushort* __restrict__ Bt,
                                          void* __restrict__ Cout,
                                          const float* __restrict__ bias,
                                          int M, int N, int K, int tM, int tN,
                                          ushort* As, ushort* Bs) {
  const int tid  = threadIdx.x;
  const int lane = tid & 63;
  const int wid  = tid >> 6;
  const int wr = (wid >> 1) * 64, wc = (wid & 1) * 64;
  const int fr = lane & 15, fk = lane >> 4;

  f32x4 acc[4][4];
#pragma unroll
  for (int m = 0; m < 4; ++m)
#pragma unroll
    for (int n = 0; n < 4; ++n) acc[m][n] = (f32x4){0.f, 0.f, 0.f, 0.f};

  const int seg0 = tid, seg1 = tid + 256;
  const int r0 = seg0 >> 2, c0 = (seg0 & 3) * 8;
  const int r1 = seg1 >> 2, c1 = (seg1 & 3) * 8;
  int ra0 = tM + r0; if (ra0 >= M) ra0 = M - 1;
  int ra1 = tM + r1; if (ra1 >= M) ra1 = M - 1;
  const int rb0 = tN + r0, rb1 = tN + r1;

#pragma unroll 1
  for (int k0 = 0; k0 < K; k0 += 32) {
    gload_lds16(&As[seg0 * 8], &A[(size_t)ra0 * K + k0 + c0]);
    gload_lds16(&As[seg1 * 8], &A[(size_t)ra1 * K + k0 + c1]);
    gload_lds16(&Bs[seg0 * 8], &Bt[(size_t)rb0 * K + k0 + c0]);
    gload_lds16(&Bs[seg1 * 8], &Bt[(size_t)rb1 * K + k0 + c1]);
    __syncthreads();
    short8 af[4], bfr[4];
#pragma unroll
    for (int m = 0; m < 4; ++m)
      af[m] = *(const short8*)&As[(wr + m * 16 + fr) * 32 + fk * 8];
#pragma unroll
    for (int n = 0; n < 4; ++n)
      bfr[n] = *(const short8*)&Bs[(wc + n * 16 + fr) * 32 + fk * 8];
#pragma unroll
    for (int m = 0; m < 4; ++m)
#pragma unroll
      for (int n = 0; n < 4; ++n)
        acc[m][n] = __builtin_amdgcn_mfma_f32_16x16x32_bf16(af[m], bfr[n], acc[m][n], 0, 0, 0);
    __syncthreads();
  }

#pragma unroll
  for (int m = 0; m < 4; ++m) {
    const int rbase = tM + wr + m * 16 + (lane >> 4) * 4;
#pragma unroll
    for (int n = 0; n < 4; ++n) {
      const int col = tN + wc + n * 16 + (lane & 15);
#pragma unroll
      for (int j = 0; j < 4; ++j) {
        int row = rbase + j;
        if (row < M) {
          float v = acc[m][n][j];
          if (OUTMODE == 0) ((ushort*)Cout)[(size_t)row * N + col] = f2bf(v);
          else              ((float*)Cout)[(size_t)row * N + col] = v + bias[col];
        }
      }
    }
  }
}

// z=0: K/V projection (M=308). z=1: IP K/V projection (M=16).
__global__ __launch_bounds__(256, 2)
void gemm_kv(const ushort* __restrict__ encb, const ushort* __restrict__ wkvT,
             ushort* __restrict__ kvb, const ushort* __restrict__ ipb,
             const ushort* __restrict__ wkvipT, ushort* __restrict__ ipkvb) {
  __shared__ ushort As[128 * 32];
  __shared__ ushort Bs[128 * 32];
  const ushort* A; const ushort* Bt; ushort* Co; int M;
  if (blockIdx.z == 0) { A = encb; Bt = wkvT;   Co = kvb;   M = B_ * STXT_; }
  else                 { A = ipb;  Bt = wkvipT; Co = ipkvb; M = B_ * TIP_;  }
  const int tM = blockIdx.x * 128;
  if (tM >= M) return;
  gemm_body<0>(A, Bt, Co, nullptr, M, KVLD, CC_, tM, blockIdx.y * 128, As, Bs);
}

// ---------------- big GEMM: 128x256 tile, BK=64, 3-buffer pipeline ----------------
// C[M][N] = A[M][K] * Bt[N][K]^T.  M%128==0, N%256==0, K%64==0, grid = (M/128)*(N/256).
// OUTMODE 1: f32 out + bias.  2: bf16 out scaled by 0.125.

// stage one K-tile (A 128x64 + B 256x64 bf16) into buf with inverse-swizzled source
__device__ __forceinline__ void stage8(const ushort* __restrict__ A,
                                       const ushort* __restrict__ Bt,
                                       ushort* buf, int K, int tM, int tN, int k0,
                                       int tid) {
#pragma unroll
  for (int c = 0; c < 2; ++c) {
    const int L = c * 8192 + tid * 16;        // byte within A region (16 KB)
    const int row = L >> 7;
    const int colb = (L & 127) ^ ((row & 7) << 4);
    gload_lds16(&buf[L >> 1], &A[(size_t)(tM + row) * K + k0 + (colb >> 1)]);
  }
#pragma unroll
  for (int c = 0; c < 4; ++c) {
    const int L = c * 8192 + tid * 16;        // byte within B region (32 KB)
    const int row = L >> 7;
    const int colb = (L & 127) ^ ((row & 7) << 4);
    gload_lds16(&buf[8192 + (L >> 1)], &Bt[(size_t)(tN + row) * K + k0 + (colb >> 1)]);
  }
}

template <int OUTMODE>
__global__ __launch_bounds__(512, 2)
void gemm8(const ushort* __restrict__ A, const ushort* __restrict__ Bt,
           void* __restrict__ Cout, const float* __restrict__ bias,
           int N, int K) {
  __shared__ ushort lds[73728];               // 3 buffers x 24576 ushorts (48 KB each)
  const int NT = K >> 6;                      // K-tiles
  int wg = blockIdx.x;
  wg = (wg & 7) * ((int)gridDim.x >> 3) + (wg >> 3);   // XCD swizzle (grid%8==0)
  const int nTn = N >> 8;
  const int tM = (wg / nTn) * 128;
  const int tN = (wg % nTn) * 256;

  const int tid = threadIdx.x, lane = tid & 63, wid = tid >> 6;
  const int wm = wid >> 2, wn = wid & 3;      // wave block: rows wm*64, cols wn*64
  const int fr = lane & 15, fk = lane >> 4;
  const int swz = (fr & 7) << 4;
  const int aRowByte = (wm * 64 + fr) * 128;
  const int bRowByte = 16384 + (wn * 64 + fr) * 128;
  const int c0b = (fk * 16) ^ swz;            // kk=0 column bytes (swizzled)
  const int c1b = (64 + fk * 16) ^ swz;       // kk=1

  f32x4 acc[4][4];
#pragma unroll
  for (int m = 0; m < 4; ++m)
#pragma unroll
    for (int n = 0; n < 4; ++n) acc[m][n] = (f32x4){0.f, 0.f, 0.f, 0.f};

  // prologue: stage K-tiles 0,1
  stage8(A, Bt, lds,         K, tM, tN, 0,  tid);
  stage8(A, Bt, lds + 24576, K, tM, tN, 64, tid);
  asm volatile("s_waitcnt vmcnt(6)" ::: "memory");   // K-tile 0 landed
  __builtin_amdgcn_s_barrier();
  __builtin_amdgcn_sched_barrier(0);

  int cur = 0;
#pragma unroll 1
  for (int kt = 0; kt < NT; ++kt) {
    // stage kt+2 into the buffer consumed in iteration kt-1
    if (kt + 2 < NT) {
      int nxt = cur + 2; if (nxt >= 3) nxt -= 3;
      stage8(A, Bt, lds + nxt * 24576, K, tM, tN, (kt + 2) * 64, tid);
    }
    const char* bc = (const char*)lds + cur * 49152;

    // P0: A frags (m0-3, kk0-1) + B frags (n0-1)
    short8 af[4][2], bA[2][2];
#pragma unroll
    for (int m = 0; m < 4; ++m) {
      af[m][0] = *(const short8*)(bc + aRowByte + m * 2048 + c0b);
      af[m][1] = *(const short8*)(bc + aRowByte + m * 2048 + c1b);
    }
#pragma unroll
    for (int n = 0; n < 2; ++n) {
      bA[n][0] = *(const short8*)(bc + bRowByte + n * 2048 + c0b);
      bA[n][1] = *(const short8*)(bc + bRowByte + n * 2048 + c1b);
    }
    __builtin_amdgcn_s_barrier();
    __builtin_amdgcn_s_setprio(1);
#pragma unroll
    for (int m = 0; m < 4; ++m)
#pragma unroll
      for (int n = 0; n < 2; ++n) {
        acc[m][n] = __builtin_amdgcn_mfma_f32_16x16x32_bf16(af[m][0], bA[n][0], acc[m][n], 0, 0, 0);
        acc[m][n] = __builtin_amdgcn_mfma_f32_16x16x32_bf16(af[m][1], bA[n][1], acc[m][n], 0, 0, 0);
      }
    __builtin_amdgcn_s_setprio(0);
    __builtin_amdgcn_s_barrier();

    // P1: B frags (n2-3)
    short8 bB[2][2];
#pragma unroll
    for (int n = 0; n < 2; ++n) {
      bB[n][0] = *(const short8*)(bc + bRowByte + (n + 2) * 2048 + c0b);
      bB[n][1] = *(const short8*)(bc + bRowByte + (n + 2) * 2048 + c1b);
    }
    __builtin_amdgcn_s_barrier();
    __builtin_amdgcn_s_setprio(1);
#pragma unroll
    for (int m = 0; m < 4; ++m)
#pragma unroll
      for (int n = 0; n < 2; ++n) {
        acc[m][n + 2] = __builtin_amdgcn_mfma_f32_16x16x32_bf16(af[m][0], bB[n][0], acc[m][n + 2], 0, 0, 0);
        acc[m][n + 2] = __builtin_amdgcn_mfma_f32_16x16x32_bf16(af[m][1], bB[n][1], acc[m][n + 2], 0, 0, 0);
      }
    __builtin_amdgcn_s_setprio(0);
    __builtin_amdgcn_sched_barrier(0);
    if (kt + 2 < NT)      asm volatile("s_waitcnt vmcnt(6)" ::: "memory");
    else if (kt + 1 < NT) asm volatile("s_waitcnt vmcnt(0)" ::: "memory");
    __builtin_amdgcn_s_barrier();
    __builtin_amdgcn_sched_barrier(0);
    cur = (cur == 2) ? 0 : cur + 1;
  }

#pragma unroll
  for (int m = 0; m < 4; ++m) {
    const int rbase = tM + wm * 64 + m * 16 + (lane >> 4) * 4;
#pragma unroll
    for (int n = 0; n < 4; ++n) {
      const int col = tN + wn * 64 + n * 16 + fr;
#pragma unroll
      for (int j = 0; j < 4; ++j) {
        float v = acc[m][n][j];
        if (OUTMODE == 2) ((ushort*)Cout)[(size_t)(rbase + j) * N + col] = f2bf(v * 0.125f);
        else              ((float*)Cout)[(size_t)(rbase + j) * N + col] = v + bias[col];
      }
    }
  }
}

// ---------------- attention (MFMA) ----------------

__global__ __launch_bounds__(256, 4)
void stats_mfma(const ushort* __restrict__ qb, const ushort* __restrict__ kvb,
                float* __restrict__ stats) {
  __shared__ ushort Ks[80 * 64];
  __shared__ float part[4][2];
  const int qt = blockIdx.x, bh = blockIdx.y;
  const int b = bh / H_, h = bh % H_;
  const int tid = threadIdx.x, lane = tid & 63, wid = tid >> 6;
  for (int c = tid; c < 80 * 8; c += 256) {
    int row = c >> 3, col = (c & 7) * 8;
    uint4 v = {0, 0, 0, 0};
    if (row < STXT_)
      v = *(const uint4*)&kvb[(size_t)(b * STXT_ + row) * KVLD + h * D_ + col];
    *(uint4*)((char*)Ks + kswz(row, col * 2)) = v;
  }
  __syncthreads();
  const int fr = lane & 15, fk = lane >> 4;
  const int wr = wid * 32;
  short8 a0[2], a1[2];
#pragma unroll
  for (int m = 0; m < 2; ++m) {
    const ushort* qp = &qb[((size_t)b * S_ + qt * 128 + wr + m * 16 + fr) * C_ + h * D_];
    a0[m] = *(const short8*)&qp[fk * 8];
    a1[m] = *(const short8*)&qp[32 + fk * 8];
  }
  f32x4 acc[2][5];
#pragma unroll
  for (int m = 0; m < 2; ++m)
#pragma unroll
    for (int n = 0; n < 5; ++n) acc[m][n] = (f32x4){0.f, 0.f, 0.f, 0.f};
#pragma unroll
  for (int n = 0; n < 5; ++n) {
    short8 b0 = *(const short8*)((const char*)Ks + kswz(n * 16 + fr, fk * 16));
    short8 b1 = *(const short8*)((const char*)Ks + kswz(n * 16 + fr, 64 + fk * 16));
#pragma unroll
    for (int m = 0; m < 2; ++m) {
      acc[m][n] = __builtin_amdgcn_mfma_f32_16x16x32_bf16(a0[m], b0, acc[m][n], 0, 0, 0);
      acc[m][n] = __builtin_amdgcn_mfma_f32_16x16x32_bf16(a1[m], b1, acc[m][n], 0, 0, 0);
    }
  }
  float sum = 0.f, ss = 0.f;
#pragma unroll
  for (int m = 0; m < 2; ++m)
#pragma unroll
    for (int n = 0; n < 5; ++n)
#pragma unroll
      for (int j = 0; j < 4; ++j) {
        float v = acc[m][n][j];
        sum += v;
        ss = fmaf(v, v, ss);
      }
#pragma unroll
  for (int msk = 1; msk < 64; msk <<= 1) {
    sum += __shfl_xor(sum, msk, 64);
    ss  += __shfl_xor(ss,  msk, 64);
  }
  if (lane == 0) { part[wid][0] = sum; part[wid][1] = ss; }
  __syncthreads();
  if (tid == 0) {
    float s = 0.f, q2 = 0.f;
#pragma unroll
    for (int w = 0; w < 4; ++w) { s += part[w][0]; q2 += part[w][1]; }
    atomicAdd(&stats[0], s);
    atomicAdd(&stats[1], q2);
  }
}

__global__ __launch_bounds__(256, 2)
void attn_mfma(const ushort* __restrict__ qb, const ushort* __restrict__ kvb,
               const ushort* __restrict__ ipkvb, const float* __restrict__ region,
               const float* __restrict__ stats, const float* __restrict__ sigma,
               ushort* __restrict__ hb) {
  __shared__ ushort Ks[96 * 64];
  __shared__ ushort Vt[64 * 104];
  __shared__ ushort Pl[128 * 104];
  const int qt = blockIdx.x, bh = blockIdx.y;
  const int b = bh / H_, h = bh % H_;
  const int tid = threadIdx.x, lane = tid & 63, wid = tid >> 6;
  const int fr = lane & 15, fk = lane >> 4;
  const int wr = wid * 32;
  const float NINF = -1e30f;

  for (int c = tid; c < 96 * 8; c += 256) {
    int row = c >> 3, col = (c & 7) * 8;
    uint4 v = {0, 0, 0, 0};
    if (row < STXT_)
      v = *(const uint4*)&kvb[(size_t)(b * STXT_ + row) * KVLD + h * D_ + col];
    else if (row >= 80 && row < 80 + TIP_)
      v = *(const uint4*)&ipkvb[(size_t)(b * TIP_ + row - 80) * KVLD + h * D_ + col];
    *(uint4*)((char*)Ks + kswz(row, col * 2)) = v;
  }
  for (int c = tid; c < 96 * 64; c += 256) {
    int k = c >> 6, d = c & 63;
    ushort v = 0;
    if (k < STXT_)
      v = kvb[(size_t)(b * STXT_ + k) * KVLD + C_ + h * D_ + d];
    else if (k >= 80 && k < 80 + TIP_)
      v = ipkvb[(size_t)(b * TIP_ + k - 80) * KVLD + C_ + h * D_ + d];
    Vt[d * 104 + k] = v;
  }
  __syncthreads();

  short8 a0[2], a1[2];
#pragma unroll
  for (int m = 0; m < 2; ++m) {
    const ushort* qp = &qb[((size_t)b * S_ + qt * 128 + wr + m * 16 + fr) * C_ + h * D_];
    a0[m] = *(const short8*)&qp[fk * 8];
    a1[m] = *(const short8*)&qp[32 + fk * 8];
  }
  f32x4 acc[2][6];
#pragma unroll
  for (int m = 0; m < 2; ++m)
#pragma unroll
    for (int n = 0; n < 6; ++n) acc[m][n] = (f32x4){0.f, 0.f, 0.f, 0.f};
#pragma unroll
  for (int n = 0; n < 6; ++n) {
    short8 b0 = *(const short8*)((const char*)Ks + kswz(n * 16 + fr, fk * 16));
    short8 b1 = *(const short8*)((const char*)Ks + kswz(n * 16 + fr, 64 + fk * 16));
#pragma unroll
    for (int m = 0; m < 2; ++m) {
      acc[m][n] = __builtin_amdgcn_mfma_f32_16x16x32_bf16(a0[m], b0, acc[m][n], 0, 0, 0);
      acc[m][n] = __builtin_amdgcn_mfma_f32_16x16x32_bf16(a1[m], b1, acc[m][n], 0, 0, 0);
    }
  }

  float bscale;
  {
    float sum = stats[0], sumsq = stats[1];
    const float Nf = (float)((double)B_ * H_ * S_ * STXT_);
    float var = (sumsq - sum * (sum / Nf)) / (Nf - 1.0f);
    bscale = sigma[0] * sqrtf(var);
  }

#pragma unroll
  for (int m = 0; m < 2; ++m) {
#pragma unroll
    for (int j = 0; j < 4; ++j) {
      const int qrow = qt * 128 + wr + m * 16 + (lane >> 4) * 4 + j;
      const float* rbase = &region[((size_t)b * S_ + qrow) * STXT_];
      float s[6];
#pragma unroll
      for (int n = 0; n < 5; ++n) {
        int key = n * 16 + fr;
        float rg = (key < STXT_) ? rbase[key] : 0.f;
        s[n] = (key < STXT_) ? fmaf(rg, bscale, acc[m][n][j]) : NINF;
      }
      s[5] = (fr < TIP_) ? acc[m][5][j] : NINF;

      float mt = fmaxf(fmaxf(fmaxf(s[0], s[1]), fmaxf(s[2], s[3])), s[4]);
#pragma unroll
      for (int msk = 1; msk < 16; msk <<= 1) mt = fmaxf(mt, __shfl_xor(mt, msk, 64));
      float pt[5], lt = 0.f;
#pragma unroll
      for (int n = 0; n < 5; ++n) { pt[n] = __expf(s[n] - mt); lt += pt[n]; }
#pragma unroll
      for (int msk = 1; msk < 16; msk <<= 1) lt += __shfl_xor(lt, msk, 64);

      float mi = s[5];
      mi = fmaxf(mi, __shfl_xor(mi, 1, 64));
      mi = fmaxf(mi, __shfl_xor(mi, 2, 64));
      float pi = __expf(s[5] - mi);
      float li = pi;
      li += __shfl_xor(li, 1, 64);
      li += __shfl_xor(li, 2, 64);

      const float rlt = 1.f / lt;
      const int prow = wr + m * 16 + (lane >> 4) * 4 + j;
#pragma unroll
      for (int n = 0; n < 5; ++n) Pl[prow * 104 + n * 16 + fr] = f2bf(pt[n] * rlt);
      Pl[prow * 104 + 80 + fr] = (fr < TIP_) ? f2bf(pi / li) : (ushort)0;
    }
  }

  f32x4 o[2][4];
#pragma unroll
  for (int m = 0; m < 2; ++m)
#pragma unroll
    for (int n = 0; n < 4; ++n) o[m][n] = (f32x4){0.f, 0.f, 0.f, 0.f};
#pragma unroll
  for (int kc = 0; kc < 3; ++kc) {
    const int kb8 = kc * 32;
    short8 pa0 = *(const short8*)&Pl[(wr + fr) * 104 + kb8 + fk * 8];
    short8 pa1 = *(const short8*)&Pl[(wr + 16 + fr) * 104 + kb8 + fk * 8];
#pragma unroll
    for (int n = 0; n < 4; ++n) {
      short8 vf = *(const short8*)&Vt[(n * 16 + fr) * 104 + kb8 + fk * 8];
      o[0][n] = __builtin_amdgcn_mfma_f32_16x16x32_bf16(pa0, vf, o[0][n], 0, 0, 0);
      o[1][n] = __builtin_amdgcn_mfma_f32_16x16x32_bf16(pa1, vf, o[1][n], 0, 0, 0);
    }
  }

#pragma unroll
  for (int m = 0; m < 2; ++m)
#pragma unroll
    for (int n = 0; n < 4; ++n)
#pragma unroll
      for (int j = 0; j < 4; ++j) {
        int row = qt * 128 + wr + m * 16 + (lane >> 4) * 4 + j;
        hb[((size_t)b * S_ + row) * C_ + h * D_ + n * 16 + fr] = f2bf(o[m][n][j]);
      }
}

// ---------------- launcher ----------------

extern "C" void kernel_launch(void* const* d_in, const int* in_sizes, int n_in,
                              void* d_out, int out_size, void* d_ws, size_t ws_size,
                              hipStream_t stream) {
  const float* hid    = (const float*)d_in[0];
  const float* enc    = (const float*)d_in[1];
  const float* ipx    = (const float*)d_in[2];
  const float* region = (const float*)d_in[3];
  const float* sigma  = (const float*)d_in[4];
  const float* wq     = (const float*)d_in[5];
  const float* wk     = (const float*)d_in[6];
  const float* wv     = (const float*)d_in[7];
  const float* wkip   = (const float*)d_in[8];
  const float* wvip   = (const float*)d_in[9];
  const float* wout   = (const float*)d_in[10];
  const float* bout   = (const float*)d_in[11];

  char* ws = (char*)d_ws;
  size_t off = 0;
  auto alloc = [&](size_t bytes) {
    char* p = ws + off;
    off += (bytes + 255) & ~(size_t)255;
    return p;
  };
  float*  stats  = (float*)alloc(16);
  ushort* hb     = (ushort*)alloc((size_t)B_ * S_ * C_ * 2);
  ushort* qb     = (ushort*)alloc((size_t)B_ * S_ * C_ * 2);   // pre-scaled by 0.125
  ushort* encb   = (ushort*)alloc((size_t)B_ * STXT_ * CC_ * 2);
  ushort* ipb    = (ushort*)alloc((size_t)B_ * TIP_ * CC_ * 2);
  ushort* wqT    = (ushort*)alloc((size_t)C_ * C_ * 2);
  ushort* wkvT   = (ushort*)alloc((size_t)KVLD * CC_ * 2);
  ushort* wkvipT = (ushort*)alloc((size_t)KVLD * CC_ * 2);
  ushort* woutT  = (ushort*)alloc((size_t)C_ * C_ * 2);
  ushort* kvb    = (ushort*)alloc((size_t)B_ * STXT_ * KVLD * 2);
  ushort* ipkvb  = (ushort*)alloc((size_t)B_ * TIP_ * KVLD * 2);

  hipMemsetAsync(stats, 0, 16, stream);
  convert_all<<<2048, 256, 0, stream>>>(hid, enc, ipx, hb, encb, ipb);
  transpose_weights<<<dim3(40, 40, 6), dim3(32, 8), 0, stream>>>(
      wq, wk, wv, wkip, wvip, wout, wqT, wkvT, wkvipT, woutT);

  gemm8<2><<<dim3((B_ * S_ / 128) * (C_ / 256)), 512, 0, stream>>>(hb, wqT, qb, nullptr, C_, C_);
  gemm_kv<<<dim3(3, 20, 2), 256, 0, stream>>>(encb, wkvT, kvb, ipb, wkvipT, ipkvb);

  stats_mfma<<<dim3(S_ / 128, B_ * H_), 256, 0, stream>>>(qb, kvb, stats);
  attn_mfma<<<dim3(S_ / 128, B_ * H_), 256, 0, stream>>>(qb, kvb, ipkvb, region,
                                                         stats, sigma, hb);
  gemm8<1><<<dim3((B_ * S_ / 128) * (C_ / 256)), 512, 0, stream>>>(hb, woutT, d_out, bout, C_, C_);
}